// Round 4
// baseline (787.457 us; speedup 1.0000x reference)
//
#include <hip/hip_runtime.h>
#include <math.h>

// SchNet interaction block, fp32. Shapes: Nb=8, Na=1024, Nnbh=64, A=F=128, S=50.
// Pipeline:
//   y = x @ W_in2f^T                                  (rowgemm, no bias)
//   per pair p: H[p,g]  = ssp(sum_s fij[p,s] W_f1[g,s] + b_f1[g])
//               Wm[p,f] = sum_g H[p,g] W_f2[f,g] + b_f2[f]
//   v[a,f] = sum_n mask*[r<=5] * y[nbr(n),f] * Wm[n,f]
//   t = ssp(ssp(v @ W_f2out^T + b_f2out))   <-- DOUBLE ssp per reference!
//   out = t @ W_dense^T + b_dense

#define RCUT  5.0f
#define LOG2F_ 0.69314718055994530942f

static __device__ __forceinline__ float sspf(float x) {
    // softplus(x) - log(2) == max(x,0) + log1p(exp(-|x|)) - log(2)
    return fmaxf(x, 0.0f) + log1pf(expf(-fabsf(x))) - LOG2F_;
}

// ---------------------------------------------------------------------------
// rowgemm: C[a][f] = act^nssp(sum_i A[a][i] * W[f][i] + bias[f])
// block = 16 atoms, 128 threads; thread t owns output feature f = t for all
// 16 atoms.  LDS: Ws[128][133] + xs[16][133] = 76608 B (pad 133 -> stride 5
// banks, gcd(5,32)=1, conflict-free).  In-place safe (A may == C): block
// stages its own 16 rows to LDS, barrier, computes, writes only those rows.
// ---------------------------------------------------------------------------
__global__ __launch_bounds__(128) void rowgemm_kernel(
    const float* A,                  // [8192][128]
    const float* __restrict__ W,     // [128][128]  [out f][in i]
    const float* __restrict__ bias,  // [128] or null
    int has_bias, int n_ssp,
    float* C)                        // [8192][128]
{
    extern __shared__ float sm[];
    float* Ws = sm;            // [128][133]
    float* xs = sm + 17024;    // [16][133]
    const int t  = threadIdx.x;        // 0..127 = output feature
    const int a0 = blockIdx.x * 16;

    for (int r = 0; r < 128; ++r)                 // coalesced: lane t reads col t
        Ws[r * 133 + t] = W[r * 128 + t];
    for (int a = 0; a < 16; ++a)
        xs[a * 133 + t] = A[(size_t)(a0 + a) * 128 + t];
    __syncthreads();

    float bb = has_bias ? bias[t] : 0.0f;
    float acc[16];
    #pragma unroll
    for (int a = 0; a < 16; ++a) acc[a] = bb;

    for (int i = 0; i < 128; ++i) {
        float w = Ws[t * 133 + i];                // conflict-free (pad 133)
        #pragma unroll
        for (int a = 0; a < 16; ++a)
            acc[a] = fmaf(xs[a * 133 + i], w, acc[a]);  // xs: broadcast read
    }
    #pragma unroll
    for (int a = 0; a < 16; ++a) {
        float o = acc[a];
        if (n_ssp >= 1) o = sspf(o);
        if (n_ssp >= 2) o = sspf(o);
        C[(size_t)(a0 + a) * 128 + t] = o;
    }
}

// ---------------------------------------------------------------------------
// Interaction: block = ONE atom (64 pairs), 256 threads.
// tx = t&31 -> f/g tile of 4 (c0 = 4*tx); ty = t>>5 -> pair tile of 8 (n0).
// LDS (floats, total 18832 = 75328 B):
//   HT [128][68]  @0      HT[g][n] = ssp(H[n][g])      (8704)
//   U             @8704   union, 10000 fl:
//     phase A: fT[50][68] @U (fT[s][n]);  W1T[50][132] @U+3400 (W1T[s][g])
//     phase B: W2T[64][132] @U   (one 64-g half of W_f2, W2T[gl][f])
//     epilog : pvb[8][132]  @U
//   cb[64] @18704, nb[64] @18768.
// ---------------------------------------------------------------------------
__global__ __launch_bounds__(256) void interaction_kernel(
    const float* __restrict__ rij,   // [8192][64]
    const int*   __restrict__ nbrs,  // [8192][64], values 0..1023 (in-batch)
    const float* __restrict__ mask,  // [8192][64]
    const float* __restrict__ fij,   // [8192][64][50]
    const float* __restrict__ W1,    // [128][50]   [g][s]
    const float* __restrict__ b1,    // [128]
    const float* __restrict__ W2,    // [128][128]  [f][g]
    const float* __restrict__ b2,    // [128]
    const float* __restrict__ y,     // [8192][128]
    float*       __restrict__ v)     // [8192][128]
{
    extern __shared__ float sm[];
    float* HT   = sm;                 // [128][68]
    float* U    = sm + 8704;
    float* fT   = U;                  // [50][68]
    float* W1T  = U + 3400;           // [50][132]
    float* W2T  = U;                  // [64][132]
    float* pvb  = U;                  // [8][132]
    float* cb   = sm + 18704;         // [64]
    int*   nb   = (int*)(sm + 18768); // [64]

    const int t  = threadIdx.x;
    const int a  = blockIdx.x;            // global atom index
    const int b  = a >> 10;               // batch
    const int p0 = a * 64;                // first pair of this atom
    const int tx = t & 31;
    const int ty = t >> 5;
    const int c0 = tx * 4;                // 4-wide f/g tile
    const int n0 = ty * 8;                // 8-wide pair tile

    // ---- stage pair coefficients + fij^T + W1^T ----
    if (t < 64) {
        float r = rij[p0 + t];
        cb[t] = (r <= RCUT) ? mask[p0 + t] : 0.0f;
        nb[t] = (b << 10) + nbrs[p0 + t];
    }
    for (int lin = t; lin < 64 * 50; lin += 256) {      // fij for 64 pairs
        int n = lin / 50, s = lin - n * 50;
        fT[s * 68 + n] = fij[(size_t)p0 * 50 + lin];    // = fij[p0+n][s]
    }
    for (int lin = t; lin < 128 * 50; lin += 256) {     // W1[g][s] -> W1T[s][g]
        int g = lin / 50, s = lin - g * 50;
        W1T[s * 132 + g] = W1[lin];
    }
    __syncthreads();                                    // B1

    // ---- phase A: H[n][g] = ssp(b1[g] + sum_s fij[n][s] W1[g][s]) ----
    float accA[4][8];
    #pragma unroll
    for (int j = 0; j < 4; ++j) {
        float bj = b1[c0 + j];
        #pragma unroll
        for (int i = 0; i < 8; ++i) accA[j][i] = bj;
    }
    for (int s = 0; s < 50; ++s) {
        float4 f0v = *(const float4*)&fT[s * 68 + n0];
        float4 f1v = *(const float4*)&fT[s * 68 + n0 + 4];
        float4 wv  = *(const float4*)&W1T[s * 132 + c0];
        float ar[8] = {f0v.x, f0v.y, f0v.z, f0v.w, f1v.x, f1v.y, f1v.z, f1v.w};
        float br[4] = {wv.x, wv.y, wv.z, wv.w};
        #pragma unroll
        for (int j = 0; j < 4; ++j)
            #pragma unroll
            for (int i = 0; i < 8; ++i)
                accA[j][i] = fmaf(br[j], ar[i], accA[j][i]);
    }
    // HT[g][n] = ssp(accA)
    #pragma unroll
    for (int j = 0; j < 4; ++j) {
        float4 h0 = make_float4(sspf(accA[j][0]), sspf(accA[j][1]),
                                sspf(accA[j][2]), sspf(accA[j][3]));
        float4 h1 = make_float4(sspf(accA[j][4]), sspf(accA[j][5]),
                                sspf(accA[j][6]), sspf(accA[j][7]));
        *(float4*)&HT[(c0 + j) * 68 + n0]     = h0;
        *(float4*)&HT[(c0 + j) * 68 + n0 + 4] = h1;
    }

    // ---- phase B: Wm[n][f] = b2[f] + sum_g H[n][g] W2[f][g] ----
    float accB[8][4];
    #pragma unroll
    for (int j = 0; j < 4; ++j) {
        float bj = b2[c0 + j];
        #pragma unroll
        for (int i = 0; i < 8; ++i) accB[i][j] = bj;
    }
    for (int h = 0; h < 2; ++h) {
        __syncthreads();   // h=0: HT visible + fT/W1T reads done; h=1: prev W2T reads done
        // stage W2T[gl][f] = W2[f][64h + gl], gl in [0,64): 2048 float4 loads
        {
            const float4* W2q = (const float4*)W2;
            #pragma unroll
            for (int r = 0; r < 8; ++r) {
                int lin4 = r * 256 + t;          // 0..2047
                int f = lin4 >> 4;               // 16 float4 per f-row half
                int q = lin4 & 15;
                float4 w = W2q[f * 32 + h * 16 + q];   // W2[f][64h+4q .. +3]
                W2T[(q * 4 + 0) * 132 + f] = w.x;
                W2T[(q * 4 + 1) * 132 + f] = w.y;
                W2T[(q * 4 + 2) * 132 + f] = w.z;
                W2T[(q * 4 + 3) * 132 + f] = w.w;
            }
        }
        __syncthreads();
        for (int gl = 0; gl < 64; ++gl) {
            int g = h * 64 + gl;
            float4 h0 = *(const float4*)&HT[g * 68 + n0];      // H[n0..+3][g]
            float4 h1 = *(const float4*)&HT[g * 68 + n0 + 4];
            float4 wv = *(const float4*)&W2T[gl * 132 + c0];   // W2[c0..+3][g]
            float hr[8] = {h0.x, h0.y, h0.z, h0.w, h1.x, h1.y, h1.z, h1.w};
            float wr[4] = {wv.x, wv.y, wv.z, wv.w};
            #pragma unroll
            for (int i = 0; i < 8; ++i)
                #pragma unroll
                for (int j = 0; j < 4; ++j)
                    accB[i][j] = fmaf(hr[i], wr[j], accB[i][j]);
        }
    }

    // ---- epilogue: pv[j] = sum_i cb[n] * y[nb[n]][c0+j] * Wm[n][c0+j] ----
    float pv[4] = {0.0f, 0.0f, 0.0f, 0.0f};
    #pragma unroll
    for (int i = 0; i < 8; ++i) {
        int n = n0 + i;
        float c = cb[n];
        const float* yrow = y + (size_t)nb[n] * 128 + c0;
        float4 yv = *(const float4*)yrow;
        float yr[4] = {yv.x, yv.y, yv.z, yv.w};
        #pragma unroll
        for (int j = 0; j < 4; ++j)
            pv[j] = fmaf(c * yr[j], accB[i][j], pv[j]);
    }
    __syncthreads();   // all W2T reads done -> U reusable as pvb
    *(float4*)&pvb[ty * 132 + c0] = make_float4(pv[0], pv[1], pv[2], pv[3]);
    __syncthreads();

    if (t < 128) {
        float s = 0.0f;
        #pragma unroll
        for (int r = 0; r < 8; ++r) s += pvb[r * 132 + t];
        v[(size_t)a * 128 + t] = s;
    }
}

// ---------------------------------------------------------------------------
extern "C" void kernel_launch(void* const* d_in, const int* in_sizes, int n_in,
                              void* d_out, int out_size, void* d_ws, size_t ws_size,
                              hipStream_t stream) {
    const float* x        = (const float*)d_in[0];
    const float* rij      = (const float*)d_in[1];
    const int*   nbrs     = (const int*)  d_in[2];
    const float* mask     = (const float*)d_in[3];
    const float* fij      = (const float*)d_in[4];
    const float* W_in2f   = (const float*)d_in[5];
    const float* W_f1     = (const float*)d_in[6];
    const float* b_f1     = (const float*)d_in[7];
    const float* W_f2     = (const float*)d_in[8];
    const float* b_f2     = (const float*)d_in[9];
    const float* W_f2out  = (const float*)d_in[10];
    const float* b_f2out  = (const float*)d_in[11];
    const float* W_dense  = (const float*)d_in[12];
    const float* b_dense  = (const float*)d_in[13];
    float* out = (float*)d_out;

    // ws: only y [8192][128] fp32 = 4 MB. v/t/out chain is in-place in d_out.
    float* y = (float*)d_ws;

    const int RG_LDS  = 19152 * 4;   // 76608 B
    const int INT_LDS = 18832 * 4;   // 75328 B
    (void)hipFuncSetAttribute((const void*)rowgemm_kernel,
        hipFuncAttributeMaxDynamicSharedMemorySize, RG_LDS);
    (void)hipFuncSetAttribute((const void*)interaction_kernel,
        hipFuncAttributeMaxDynamicSharedMemorySize, INT_LDS);

    // K1: y = x @ W_in2f^T
    rowgemm_kernel<<<512, 128, RG_LDS, stream>>>(x, W_in2f, nullptr, 0, 0, y);
    // K2: filter net + cutoff + gather + aggregate -> d_out
    interaction_kernel<<<8192, 256, INT_LDS, stream>>>(
        rij, nbrs, mask, fij, W_f1, b_f1, W_f2, b_f2, y, out);
    // K3a: t = ssp(ssp(v @ W_f2out^T + b_f2out)) — DOUBLE ssp per reference
    rowgemm_kernel<<<512, 128, RG_LDS, stream>>>(out, W_f2out, b_f2out, 1, 2, out);
    // K3b: out = t @ W_dense^T + b_dense, in-place
    rowgemm_kernel<<<512, 128, RG_LDS, stream>>>(out, W_dense, b_dense, 1, 0, out);
}

// Round 5
// 679.643 us; speedup vs baseline: 1.1586x; 1.1586x over previous
//
#include <hip/hip_runtime.h>
#include <math.h>

// SchNet interaction, MFMA-accelerated. Nb=8, Na=1024, Nnbh=64, A=F=128, S=50.
//   y = x @ W_in2f^T
//   H[n,g]  = ssp(fij[n,:] . W1[g,:] + b1[g])     (per pair, MFMA bf16 split)
//   Wm[n,f] = H[n,:] . W2[f,:] + b2[f]            (MFMA bf16 split)
//   v[a,f]  = sum_n mask*[r<=5] * y[nbr(n),f] * Wm[n,f]
//   t = ssp(ssp(v @ W_f2out^T + b_f2out));  out = t @ W_dense^T + b_dense

#define RCUT  5.0f
#define LOG2F_ 0.69314718055994530942f

typedef __bf16 bf16x8_t __attribute__((ext_vector_type(8)));
typedef float  f32x4_t  __attribute__((ext_vector_type(4)));

static __device__ __forceinline__ float sspf(float x) {
    return fmaxf(x, 0.0f) + log1pf(expf(-fabsf(x))) - LOG2F_;
}
static __device__ __forceinline__ unsigned pack2(__bf16 a, __bf16 b) {
    union { __bf16 h[2]; unsigned u; } un; un.h[0] = a; un.h[1] = b; return un.u;
}

// ---------------------------------------------------------------------------
// gemm128 (fp32, VALU): C[a][f] = ssp^n(sum_i A[a][i] W[f][i] + bias[f])
// 64 atoms/block, 256 threads, 4x8 reg tile. LDS 102400 B.
// In-place safe (A may == C): stage-own-rows -> barrier -> compute -> write.
// ---------------------------------------------------------------------------
__global__ __launch_bounds__(256) void gemm128_kernel(
    const float* A, const float* __restrict__ W, const float* __restrict__ bias,
    int has_bias, int n_ssp, float* C)
{
    extern __shared__ float sm[];
    float* WT = sm;            // [128][132]  WT[i][f] = W[f][i]
    float* xT = sm + 16896;    // [128][68]   xT[i][a] = A[atom0+a][i]
    const int t = threadIdx.x;
    const int atom0 = blockIdx.x * 64;

    const float4* W4 = (const float4*)W;
    #pragma unroll
    for (int r = 0; r < 16; ++r) {
        int lin4 = r * 256 + t;
        int f = lin4 >> 5, i4 = lin4 & 31;
        float4 w = W4[lin4];
        WT[(i4 * 4 + 0) * 132 + f] = w.x;
        WT[(i4 * 4 + 1) * 132 + f] = w.y;
        WT[(i4 * 4 + 2) * 132 + f] = w.z;
        WT[(i4 * 4 + 3) * 132 + f] = w.w;
    }
    const float4* A4 = (const float4*)(A + (size_t)atom0 * 128);
    #pragma unroll
    for (int r = 0; r < 8; ++r) {
        int lin4 = r * 256 + t;
        int a = lin4 >> 5, i4 = lin4 & 31;
        float4 xv = A4[lin4];
        xT[(i4 * 4 + 0) * 68 + a] = xv.x;
        xT[(i4 * 4 + 1) * 68 + a] = xv.y;
        xT[(i4 * 4 + 2) * 68 + a] = xv.z;
        xT[(i4 * 4 + 3) * 68 + a] = xv.w;
    }
    __syncthreads();

    const int f0 = (t & 15) * 8;
    const int a0 = (t >> 4) * 4;
    float acc[4][8];
    #pragma unroll
    for (int i = 0; i < 4; ++i)
        #pragma unroll
        for (int j = 0; j < 8; ++j) acc[i][j] = 0.0f;

    #pragma unroll 4
    for (int k = 0; k < 128; ++k) {
        float4 av = *(const float4*)&xT[k * 68 + a0];
        float4 b0 = *(const float4*)&WT[k * 132 + f0];
        float4 b1 = *(const float4*)&WT[k * 132 + f0 + 4];
        float ar[4] = {av.x, av.y, av.z, av.w};
        float br[8] = {b0.x, b0.y, b0.z, b0.w, b1.x, b1.y, b1.z, b1.w};
        #pragma unroll
        for (int i = 0; i < 4; ++i)
            #pragma unroll
            for (int j = 0; j < 8; ++j)
                acc[i][j] = fmaf(ar[i], br[j], acc[i][j]);
    }

    float bb[8];
    if (has_bias) {
        float4 q0 = *(const float4*)(bias + f0);
        float4 q1 = *(const float4*)(bias + f0 + 4);
        bb[0]=q0.x; bb[1]=q0.y; bb[2]=q0.z; bb[3]=q0.w;
        bb[4]=q1.x; bb[5]=q1.y; bb[6]=q1.z; bb[7]=q1.w;
    } else {
        #pragma unroll
        for (int j = 0; j < 8; ++j) bb[j] = 0.0f;
    }
    #pragma unroll
    for (int i = 0; i < 4; ++i) {
        float o[8];
        #pragma unroll
        for (int j = 0; j < 8; ++j) {
            float val = acc[i][j] + bb[j];
            if (n_ssp >= 1) val = sspf(val);
            if (n_ssp >= 2) val = sspf(val);
            o[j] = val;
        }
        float* crow = C + (size_t)(atom0 + a0 + i) * 128 + f0;
        *(float4*)crow       = make_float4(o[0], o[1], o[2], o[3]);
        *(float4*)(crow + 4) = make_float4(o[4], o[5], o[6], o[7]);
    }
}

// ---------------------------------------------------------------------------
// Interaction kernel: 1 atom/block (64 pairs), 256 threads = 4 waves.
// MFMA 16x16x32 bf16, data operands (fij, H) split hi/lo (2-pass),
// weights single bf16. Fragment maps (m89/m120-verified):
//   A[m=lane&15][k=(lane>>4)*8+j],  B[k=(lane>>4)*8+j][n=lane&15],
//   D col=lane&15, row=(lane>>4)*4+reg.
// LDS (float offsets), total 18592 fl = 74368 B -> 2 blocks/CU:
//   Hhi bf16[64][136] @0      Hlo @4352
//   U @8704:  phase A: fhi bf16[64][72]@U, flo @U+2304, W1b bf16[128][72]@U+4608
//             phase B: W2b bf16[128][136]@U
//   cb[64]@17920  nb[64]@17984  vacc[4][136]@18048
// Strides 72/136 bf16 (36/68 dwords, ==4 mod 32) put all b128 frag reads at
// the 8-dword/bank volume floor (no conflicts beyond data volume).
// ---------------------------------------------------------------------------
__global__ __launch_bounds__(256) void interaction_kernel(
    const float* __restrict__ rij,   // [8192][64]
    const int*   __restrict__ nbrs,  // [8192][64]
    const float* __restrict__ mask,  // [8192][64]
    const float* __restrict__ fij,   // [8192][64][50]
    const float* __restrict__ W1,    // [128][50]
    const float* __restrict__ b1,    // [128]
    const float* __restrict__ W2,    // [128][128]
    const float* __restrict__ b2,    // [128]
    const float* __restrict__ y,     // [8192][128]
    float*       __restrict__ v)     // [8192][128]
{
    extern __shared__ float sm[];
    __bf16* Hhi = (__bf16*)(sm + 0);       // [64][136]
    __bf16* Hlo = (__bf16*)(sm + 4352);
    __bf16* fhi = (__bf16*)(sm + 8704);    // [64][72]
    __bf16* flo = (__bf16*)(sm + 11008);
    __bf16* W1b = (__bf16*)(sm + 13312);   // [128][72]
    __bf16* W2b = (__bf16*)(sm + 8704);    // [128][136] (union with fij/W1)
    float*  cb  = sm + 17920;              // [64]
    int*    nb  = (int*)(sm + 17984);      // [64]
    float*  vacc= sm + 18048;              // [4][136]

    const int t  = threadIdx.x;
    const int a  = blockIdx.x;
    const int b  = a >> 10;
    const int p0 = a * 64;
    const int w  = t >> 6;     // wave
    const int l  = t & 63;
    const int m  = l & 15;
    const int q  = l >> 4;

    // ---- stage: cutoffs, fij(split), W1 ----
    if (t < 64) {
        float r = rij[p0 + t];
        cb[t] = (r <= RCUT) ? mask[p0 + t] : 0.0f;
        nb[t] = (b << 10) + nbrs[p0 + t];
    }
    for (int i = t; i < 544; i += 256) vacc[i] = 0.0f;
    {
        const float2* f2 = (const float2*)(fij + (size_t)p0 * 50);
        unsigned* fhiU = (unsigned*)fhi;
        unsigned* floU = (unsigned*)flo;
        for (int i = t; i < 1600; i += 256) {          // 64x50, pairs of floats
            int lin = i * 2, n = lin / 50, s = lin - n * 50;
            float2 xv = f2[i];
            __bf16 h0 = (__bf16)xv.x, h1 = (__bf16)xv.y;
            __bf16 l0 = (__bf16)(xv.x - (float)h0), l1 = (__bf16)(xv.y - (float)h1);
            int idx = (n * 72 + s) >> 1;
            fhiU[idx] = pack2(h0, h1);
            floU[idx] = pack2(l0, l1);
        }
        for (int i = t; i < 704; i += 256) {           // zero-pad s=50..71
            int n = i / 11, s2 = i - n * 11;
            int idx = n * 36 + 25 + s2;
            fhiU[idx] = 0u; floU[idx] = 0u;
        }
        const float2* w1p = (const float2*)W1;
        unsigned* WU = (unsigned*)W1b;
        for (int i = t; i < 3200; i += 256) {          // 128x50
            int lin = i * 2, g = lin / 50, s = lin - g * 50;
            float2 xv = w1p[i];
            WU[(g * 72 + s) >> 1] = pack2((__bf16)xv.x, (__bf16)xv.y);
        }
        for (int i = t; i < 1408; i += 256) {
            int g = i / 11, s2 = i - g * 11;
            WU[g * 36 + 25 + s2] = 0u;
        }
    }
    __syncthreads();                                   // B1

    // ---- phase A: H = ssp(fij @ W1^T + b1), M=64 N=128 K=64(pad) ----
    bf16x8_t fa_h[2], fa_l[2];
    #pragma unroll
    for (int kq = 0; kq < 2; ++kq) {
        int off = (16 * w + m) * 72 + 32 * kq + 8 * q;
        fa_h[kq] = *(const bf16x8_t*)&fhi[off];
        fa_l[kq] = *(const bf16x8_t*)&flo[off];
    }
    #pragma unroll
    for (int gt = 0; gt < 8; ++gt) {
        int g = 16 * gt + m;
        bf16x8_t wb0 = *(const bf16x8_t*)&W1b[g * 72 + 8 * q];
        bf16x8_t wb1 = *(const bf16x8_t*)&W1b[g * 72 + 32 + 8 * q];
        float bv = b1[g];
        f32x4_t acc = {bv, bv, bv, bv};
        acc = __builtin_amdgcn_mfma_f32_16x16x32_bf16(fa_h[0], wb0, acc, 0, 0, 0);
        acc = __builtin_amdgcn_mfma_f32_16x16x32_bf16(fa_l[0], wb0, acc, 0, 0, 0);
        acc = __builtin_amdgcn_mfma_f32_16x16x32_bf16(fa_h[1], wb1, acc, 0, 0, 0);
        acc = __builtin_amdgcn_mfma_f32_16x16x32_bf16(fa_l[1], wb1, acc, 0, 0, 0);
        #pragma unroll
        for (int r = 0; r < 4; ++r) {
            int n = 16 * w + 4 * q + r;
            float hv = sspf(acc[r]);
            __bf16 hh = (__bf16)hv;
            __bf16 hl = (__bf16)(hv - (float)hh);
            Hhi[n * 136 + g] = hh;
            Hlo[n * 136 + g] = hl;
        }
    }
    __syncthreads();                                   // B2 (phase-A reads done)

    // ---- stage W2 -> bf16 into union ----
    {
        const float4* W4 = (const float4*)W2;
        unsigned* WU = (unsigned*)W2b;
        #pragma unroll
        for (int rr = 0; rr < 16; ++rr) {
            int i = rr * 256 + t;                      // 0..4095
            int f = i >> 5, qq = i & 31;
            float4 xv = W4[i];
            int idx = f * 68 + 2 * qq;
            WU[idx]     = pack2((__bf16)xv.x, (__bf16)xv.y);
            WU[idx + 1] = pack2((__bf16)xv.z, (__bf16)xv.w);
        }
    }
    __syncthreads();                                   // B3

    // ---- phase B: Wm = H @ W2^T + b2, fused epilogue ----
    bf16x8_t ha_h[4], ha_l[4];
    #pragma unroll
    for (int kq = 0; kq < 4; ++kq) {
        int off = (16 * w + m) * 136 + 32 * kq + 8 * q;
        ha_h[kq] = *(const bf16x8_t*)&Hhi[off];
        ha_l[kq] = *(const bf16x8_t*)&Hlo[off];
    }
    float cr[4]; const float* yr[4];
    #pragma unroll
    for (int r = 0; r < 4; ++r) {
        int n = 16 * w + 4 * q + r;
        cr[r] = cb[n];
        yr[r] = y + (size_t)nb[n] * 128;
    }
    float* vrow = vacc + w * 136;
    #pragma unroll
    for (int ft = 0; ft < 8; ++ft) {
        int f = 16 * ft + m;
        float bv = b2[f];
        f32x4_t acc = {bv, bv, bv, bv};
        #pragma unroll
        for (int kq = 0; kq < 4; ++kq) {
            bf16x8_t wb = *(const bf16x8_t*)&W2b[f * 136 + 32 * kq + 8 * q];
            acc = __builtin_amdgcn_mfma_f32_16x16x32_bf16(ha_h[kq], wb, acc, 0, 0, 0);
            acc = __builtin_amdgcn_mfma_f32_16x16x32_bf16(ha_l[kq], wb, acc, 0, 0, 0);
        }
        float s = 0.0f;
        #pragma unroll
        for (int r = 0; r < 4; ++r)
            s = fmaf(cr[r] * yr[r][f], acc[r], s);     // c_n * y[nbr][f] * Wm[n][f]
        s += __shfl_xor(s, 16);
        s += __shfl_xor(s, 32);
        if (q == 0) vrow[f] += s;                      // per-wave accumulator
    }
    __syncthreads();                                   // B4
    if (t < 128)
        v[(size_t)a * 128 + t] =
            vacc[t] + vacc[136 + t] + vacc[272 + t] + vacc[408 + t];
}

// ---------------------------------------------------------------------------
extern "C" void kernel_launch(void* const* d_in, const int* in_sizes, int n_in,
                              void* d_out, int out_size, void* d_ws, size_t ws_size,
                              hipStream_t stream) {
    const float* x        = (const float*)d_in[0];
    const float* rij      = (const float*)d_in[1];
    const int*   nbrs     = (const int*)  d_in[2];
    const float* mask     = (const float*)d_in[3];
    const float* fij      = (const float*)d_in[4];
    const float* W_in2f   = (const float*)d_in[5];
    const float* W_f1     = (const float*)d_in[6];
    const float* b_f1     = (const float*)d_in[7];
    const float* W_f2     = (const float*)d_in[8];
    const float* b_f2     = (const float*)d_in[9];
    const float* W_f2out  = (const float*)d_in[10];
    const float* b_f2out  = (const float*)d_in[11];
    const float* W_dense  = (const float*)d_in[12];
    const float* b_dense  = (const float*)d_in[13];
    float* out = (float*)d_out;
    float* y   = (float*)d_ws;        // [8192][128] fp32 = 4 MB (== out size)

    const int GEMM_LDS = 25600 * 4;   // 102400 B
    const int INT_LDS  = 18592 * 4;   // 74368 B
    (void)hipFuncSetAttribute((const void*)gemm128_kernel,
        hipFuncAttributeMaxDynamicSharedMemorySize, GEMM_LDS);
    (void)hipFuncSetAttribute((const void*)interaction_kernel,
        hipFuncAttributeMaxDynamicSharedMemorySize, INT_LDS);

    // K1: y = x @ W_in2f^T
    gemm128_kernel<<<128, 256, GEMM_LDS, stream>>>(x, W_in2f, nullptr, 0, 0, y);
    // K2: filter net + cutoff + gather + aggregate -> d_out
    interaction_kernel<<<8192, 256, INT_LDS, stream>>>(
        rij, nbrs, mask, fij, W_f1, b_f1, W_f2, b_f2, y, out);
    // K3a: t = ssp(ssp(v @ W_f2out^T + b_f2out)), in-place
    gemm128_kernel<<<128, 256, GEMM_LDS, stream>>>(out, W_f2out, b_f2out, 1, 2, out);
    // K3b: out = t @ W_dense^T + b_dense, in-place
    gemm128_kernel<<<128, 256, GEMM_LDS, stream>>>(out, W_dense, b_dense, 1, 0, out);
}

// Round 6
// 361.862 us; speedup vs baseline: 2.1761x; 1.8782x over previous
//
#include <hip/hip_runtime.h>
#include <math.h>

// SchNet interaction, MFMA bf16-split, spill-free (launch_bounds(256,2)).
// Nb=8, Na=1024, Nnbh=64, A=F=128, S=50.

#define RCUT  5.0f
#define LOG2F_ 0.69314718055994530942f

typedef __bf16 bf16x8_t __attribute__((ext_vector_type(8)));
typedef float  f32x4_t  __attribute__((ext_vector_type(4)));

static __device__ __forceinline__ float sspf(float x) {
    return fmaxf(x, 0.0f) + __logf(1.0f + __expf(-fabsf(x))) - LOG2F_;
}
static __device__ __forceinline__ unsigned pack2h(__bf16 a, __bf16 b) {
    union { __bf16 h[2]; unsigned u; } un; un.h[0] = a; un.h[1] = b; return un.u;
}
static __device__ __forceinline__ unsigned pack2f(float a, float b) {
    return pack2h((__bf16)a, (__bf16)b);
}

// ---------------------------------------------------------------------------
// K0 prep: one-time weight conversion into ws (u32 = packed bf16 pairs).
//   W1B [128][32]u32: W_f1 [g][50] -> bf16, K zero-padded to 64.     @0
//   W2B [128][64]u32: W_f2 -> single bf16.                           @4096
//   For L in {in2f, f2out, dense}: Wh/Wl [128][64]u32 hi/lo split.
//     hi @12288 + L*16384, lo = hi + 8192.
// Total 61440 u32 = 240 KB. Grid 144x256 covers 36864 work items exactly.
// ---------------------------------------------------------------------------
__global__ __launch_bounds__(256) void prep_kernel(
    const float* __restrict__ W1, const float* __restrict__ W2,
    const float* __restrict__ Wa, const float* __restrict__ Wb,
    const float* __restrict__ Wc, unsigned* __restrict__ prep)
{
    for (int i = blockIdx.x * 256 + threadIdx.x; i < 36864; i += gridDim.x * 256) {
        if (i < 4096) {
            int g = i >> 5, u = i & 31, k = 2 * u;
            float a = (k < 50)     ? W1[g * 50 + k]     : 0.0f;
            float b = (k + 1 < 50) ? W1[g * 50 + k + 1] : 0.0f;
            prep[i] = pack2f(a, b);
        } else if (i < 12288) {
            int j = i - 4096;
            float2 w = ((const float2*)W2)[j];
            prep[i] = pack2f(w.x, w.y);
        } else {
            int j = i - 12288;
            int L = j >> 13, r = j & 8191;
            const float* src = (L == 0) ? Wa : (L == 1) ? Wb : Wc;
            float2 w = ((const float2*)src)[r];
            __bf16 h0 = (__bf16)w.x, h1 = (__bf16)w.y;
            unsigned* H = prep + 12288 + L * 16384;
            H[r]        = pack2h(h0, h1);
            H[r + 8192] = pack2f(w.x - (float)h0, w.y - (float)h1);
        }
    }
}

// ---------------------------------------------------------------------------
// mgemm: C[a][f] = ssp^n(sum_k A[a][k] W[f][k] + bias[f]); MFMA 16x16x32 bf16,
// A split hi/lo in-kernel, W pre-split (prep). 3-pass: AhWh + AhWl + AlWh.
// Block: 256 thr (4 waves), 64 atoms; wave w owns rows 16w..16w+15, all 128 f.
// LDS (dwords): Ah[64][136]bf16 @0 (4352), Al @4352,
//   WhL[128][72]bf16 @8704 (4608), WlL @13312.  17920 dw = 71680 B, 2 blk/CU.
// In-place safe (A may == C): A staged fully before any C write.
// ---------------------------------------------------------------------------
__global__ __launch_bounds__(256, 2) void mgemm_kernel(
    const float* A, const unsigned* __restrict__ Wh,
    const unsigned* __restrict__ Wl, const float* __restrict__ bias,
    int n_ssp, float* C)
{
    extern __shared__ float smf[];
    __bf16*   Ah  = (__bf16*)smf;              // [64][136]
    __bf16*   Al  = (__bf16*)(smf + 4352);
    unsigned* WhU = (unsigned*)(smf + 8704);   // [128][36] u32 view
    unsigned* WlU = (unsigned*)(smf + 13312);
    __bf16*   WhB = (__bf16*)WhU;              // [128][72]
    __bf16*   WlB = (__bf16*)WlU;

    const int t = threadIdx.x;
    const int atom0 = blockIdx.x * 64;
    const int w = t >> 6, l = t & 63, m = l & 15, q = l >> 4;

    // stage A split hi/lo
    {
        const float4* A4 = (const float4*)(A + (size_t)atom0 * 128);
        unsigned* AhU = (unsigned*)Ah;
        unsigned* AlU = (unsigned*)Al;
        #pragma unroll
        for (int r = 0; r < 8; ++r) {
            int lin4 = r * 256 + t;            // 2048 float4s
            int a = lin4 >> 5, k4 = lin4 & 31;
            float4 xv = A4[lin4];
            __bf16 h0=(__bf16)xv.x, h1=(__bf16)xv.y, h2=(__bf16)xv.z, h3=(__bf16)xv.w;
            int idx = a * 68 + 2 * k4;
            AhU[idx]     = pack2h(h0, h1);
            AhU[idx + 1] = pack2h(h2, h3);
            AlU[idx]     = pack2f(xv.x - (float)h0, xv.y - (float)h1);
            AlU[idx + 1] = pack2f(xv.z - (float)h2, xv.w - (float)h3);
        }
    }

    float bb[8];
    #pragma unroll
    for (int ft = 0; ft < 8; ++ft) bb[ft] = bias ? bias[16 * ft + m] : 0.0f;
    f32x4_t acc[8];
    #pragma unroll
    for (int ft = 0; ft < 8; ++ft) acc[ft] = (f32x4_t){bb[ft], bb[ft], bb[ft], bb[ft]};

    for (int kh = 0; kh < 2; ++kh) {
        // stage W K-half (pure uint4 copies from prep)
        #pragma unroll
        for (int r = 0; r < 4; ++r) {
            int lin4 = r * 256 + t;            // 1024
            int f = lin4 >> 3, u4 = lin4 & 7;
            uint4 xh = *(const uint4*)(Wh + f * 64 + kh * 32 + 4 * u4);
            uint4 xl = *(const uint4*)(Wl + f * 64 + kh * 32 + 4 * u4);
            *(uint4*)&WhU[f * 36 + 4 * u4] = xh;
            *(uint4*)&WlU[f * 36 + 4 * u4] = xl;
        }
        __syncthreads();                       // A + W(kh) visible

        bf16x8_t ah[2], al[2];
        #pragma unroll
        for (int kq = 0; kq < 2; ++kq) {
            int off = (16 * w + m) * 136 + 64 * kh + 32 * kq + 8 * q;
            ah[kq] = *(const bf16x8_t*)&Ah[off];
            al[kq] = *(const bf16x8_t*)&Al[off];
        }
        #pragma unroll
        for (int ft = 0; ft < 8; ++ft) {
            #pragma unroll
            for (int kq = 0; kq < 2; ++kq) {
                int woff = (16 * ft + m) * 72 + 32 * kq + 8 * q;
                bf16x8_t wh = *(const bf16x8_t*)&WhB[woff];
                bf16x8_t wl = *(const bf16x8_t*)&WlB[woff];
                acc[ft] = __builtin_amdgcn_mfma_f32_16x16x32_bf16(ah[kq], wh, acc[ft], 0, 0, 0);
                acc[ft] = __builtin_amdgcn_mfma_f32_16x16x32_bf16(ah[kq], wl, acc[ft], 0, 0, 0);
                acc[ft] = __builtin_amdgcn_mfma_f32_16x16x32_bf16(al[kq], wh, acc[ft], 0, 0, 0);
            }
        }
        __syncthreads();                       // reads done before restage
    }

    #pragma unroll
    for (int ft = 0; ft < 8; ++ft)
        #pragma unroll
        for (int r = 0; r < 4; ++r) {
            float o = acc[ft][r];
            if (n_ssp >= 1) o = sspf(o);
            if (n_ssp >= 2) o = sspf(o);
            C[(size_t)(atom0 + 16 * w + 4 * q + r) * 128 + 16 * ft + m] = o;
        }
}

// ---------------------------------------------------------------------------
// Interaction: 1 atom/block (64 pairs), 256 thr = 4 waves, MFMA bf16.
// fij & H split hi/lo; W1/W2 single bf16 from prep (pure copies).
// LDS (dwords, 18592 = 74368 B -> 2 blk/CU):
//   Hh[64][136]bf16 @0, Hl @4352
//   U @8704: phA: fh[64][72] @8704, fl @11008, W1L[128][72] @13312 (->17920)
//            phB: W2L[128][136] @8704 (->17408)
//   cb[64]f @17920, nb[64]i @17984, vacc[4][136]f @18048
// ---------------------------------------------------------------------------
__global__ __launch_bounds__(256, 2) void interaction_kernel(
    const float* __restrict__ rij, const int* __restrict__ nbrs,
    const float* __restrict__ mask, const float* __restrict__ fij,
    const float* __restrict__ b1, const float* __restrict__ b2,
    const unsigned* __restrict__ W1B,   // prep [128][32] u32
    const unsigned* __restrict__ W2B,   // prep [128][64] u32
    const float* __restrict__ y, float* __restrict__ v)
{
    extern __shared__ float smf[];
    __bf16*   Hh  = (__bf16*)smf;               // [64][136]
    __bf16*   Hl  = (__bf16*)(smf + 4352);
    __bf16*   fh  = (__bf16*)(smf + 8704);      // [64][72]
    __bf16*   fl  = (__bf16*)(smf + 11008);
    unsigned* W1U = (unsigned*)(smf + 13312);   // [128][36] u32 view
    __bf16*   W1L = (__bf16*)W1U;               // [128][72]
    unsigned* W2U = (unsigned*)(smf + 8704);    // [128][68] u32 view (union)
    __bf16*   W2L = (__bf16*)W2U;               // [128][136]
    float*    cb  = smf + 17920;
    int*      nb  = (int*)(smf + 17984);
    float*    vacc = smf + 18048;               // [4][136]

    const int t  = threadIdx.x;
    const int a  = blockIdx.x;
    const int bi = a >> 10;
    const int p0 = a * 64;
    const int w  = t >> 6, l = t & 63, m = l & 15, q = l >> 4;

    // ---- stage: cutoffs, fij split, W1 copy ----
    if (t < 64) {
        float r = rij[p0 + t];
        cb[t] = (r <= RCUT) ? mask[p0 + t] : 0.0f;
        nb[t] = (bi << 10) + nbrs[p0 + t];
    }
    for (int i = t; i < 544; i += 256) vacc[i] = 0.0f;
    {
        const float2* f2 = (const float2*)(fij + (size_t)p0 * 50);
        unsigned* fhU = (unsigned*)fh;
        unsigned* flU = (unsigned*)fl;
        for (int i = t; i < 1600; i += 256) {          // 64x50 in float pairs
            int lin = i * 2, n = lin / 50, s = lin - n * 50;
            float2 xv = f2[i];
            __bf16 h0 = (__bf16)xv.x, h1 = (__bf16)xv.y;
            int idx = n * 36 + (s >> 1);
            fhU[idx] = pack2h(h0, h1);
            flU[idx] = pack2f(xv.x - (float)h0, xv.y - (float)h1);
        }
        for (int i = t; i < 448; i += 256) {           // zero-pad k=50..63
            int n = i / 7, s2 = i - n * 7;
            fhU[n * 36 + 25 + s2] = 0u;
            flU[n * 36 + 25 + s2] = 0u;
        }
        #pragma unroll
        for (int r = 0; r < 4; ++r) {                  // W1: 1024 uint4 copies
            int lin4 = r * 256 + t;
            int g = lin4 >> 3, u4 = lin4 & 7;
            *(uint4*)&W1U[g * 36 + 4 * u4] = *(const uint4*)(W1B + g * 32 + 4 * u4);
        }
    }
    __syncthreads();                                   // B1

    // ---- phase A: H = ssp(fij @ W1^T + b1), K=64 ----
    {
        float bb1[8];
        #pragma unroll
        for (int gt = 0; gt < 8; ++gt) bb1[gt] = b1[16 * gt + m];
        bf16x8_t fah[2], fal[2];
        #pragma unroll
        for (int kq = 0; kq < 2; ++kq) {
            int off = (16 * w + m) * 72 + 32 * kq + 8 * q;
            fah[kq] = *(const bf16x8_t*)&fh[off];
            fal[kq] = *(const bf16x8_t*)&fl[off];
        }
        #pragma unroll
        for (int gt = 0; gt < 8; ++gt) {
            int g = 16 * gt + m;
            bf16x8_t wb0 = *(const bf16x8_t*)&W1L[g * 72 + 8 * q];
            bf16x8_t wb1 = *(const bf16x8_t*)&W1L[g * 72 + 32 + 8 * q];
            f32x4_t acc = {bb1[gt], bb1[gt], bb1[gt], bb1[gt]};
            acc = __builtin_amdgcn_mfma_f32_16x16x32_bf16(fah[0], wb0, acc, 0, 0, 0);
            acc = __builtin_amdgcn_mfma_f32_16x16x32_bf16(fal[0], wb0, acc, 0, 0, 0);
            acc = __builtin_amdgcn_mfma_f32_16x16x32_bf16(fah[1], wb1, acc, 0, 0, 0);
            acc = __builtin_amdgcn_mfma_f32_16x16x32_bf16(fal[1], wb1, acc, 0, 0, 0);
            #pragma unroll
            for (int r = 0; r < 4; ++r) {
                int n = 16 * w + 4 * q + r;
                float hv = sspf(acc[r]);
                __bf16 hhv = (__bf16)hv;
                Hh[n * 136 + g] = hhv;
                Hl[n * 136 + g] = (__bf16)(hv - (float)hhv);
            }
        }
    }
    __syncthreads();                                   // B2 (phase-A reads done)

    // ---- stage W2 (pure uint4 copies into union) ----
    #pragma unroll
    for (int r = 0; r < 8; ++r) {                      // 2048 uint4 copies
        int lin4 = r * 256 + t;
        int f = lin4 >> 4, u4 = lin4 & 15;
        *(uint4*)&W2U[f * 68 + 4 * u4] = *(const uint4*)(W2B + f * 64 + 4 * u4);
    }
    __syncthreads();                                   // B3

    // ---- phase B: Wm = H @ W2^T + b2, fused gather/aggregate ----
    {
        bf16x8_t hhf[4], hlf[4];
        #pragma unroll
        for (int kq = 0; kq < 4; ++kq) {
            int off = (16 * w + m) * 136 + 32 * kq + 8 * q;
            hhf[kq] = *(const bf16x8_t*)&Hh[off];
            hlf[kq] = *(const bf16x8_t*)&Hl[off];
        }
        float cr[4]; const float* yp[4];
        #pragma unroll
        for (int r = 0; r < 4; ++r) {
            int n = 16 * w + 4 * q + r;
            cr[r] = cb[n];
            yp[r] = y + (size_t)nb[n] * 128;
        }
        float yv[8][4], bb2[8];
        #pragma unroll
        for (int ft = 0; ft < 8; ++ft) {
            bb2[ft] = b2[16 * ft + m];
            #pragma unroll
            for (int r = 0; r < 4; ++r) yv[ft][r] = yp[r][16 * ft + m];
        }
        #pragma unroll
        for (int ft = 0; ft < 8; ++ft) {
            int f = 16 * ft + m;
            f32x4_t acc = {bb2[ft], bb2[ft], bb2[ft], bb2[ft]};
            #pragma unroll
            for (int kq = 0; kq < 4; ++kq) {
                bf16x8_t wb = *(const bf16x8_t*)&W2L[f * 136 + 32 * kq + 8 * q];
                acc = __builtin_amdgcn_mfma_f32_16x16x32_bf16(hhf[kq], wb, acc, 0, 0, 0);
                acc = __builtin_amdgcn_mfma_f32_16x16x32_bf16(hlf[kq], wb, acc, 0, 0, 0);
            }
            float s = 0.0f;
            #pragma unroll
            for (int r = 0; r < 4; ++r)
                s = fmaf(cr[r] * yv[ft][r], acc[r], s);
            s += __shfl_xor(s, 16);
            s += __shfl_xor(s, 32);
            if (q == 0) vacc[w * 136 + f] += s;
        }
    }
    __syncthreads();                                   // B4
    if (t < 128)
        v[(size_t)a * 128 + t] =
            vacc[t] + vacc[136 + t] + vacc[272 + t] + vacc[408 + t];
}

// ---------------------------------------------------------------------------
extern "C" void kernel_launch(void* const* d_in, const int* in_sizes, int n_in,
                              void* d_out, int out_size, void* d_ws, size_t ws_size,
                              hipStream_t stream) {
    const float* x        = (const float*)d_in[0];
    const float* rij      = (const float*)d_in[1];
    const int*   nbrs     = (const int*)  d_in[2];
    const float* mask     = (const float*)d_in[3];
    const float* fij      = (const float*)d_in[4];
    const float* W_in2f   = (const float*)d_in[5];
    const float* W_f1     = (const float*)d_in[6];
    const float* b_f1     = (const float*)d_in[7];
    const float* W_f2     = (const float*)d_in[8];
    const float* b_f2     = (const float*)d_in[9];
    const float* W_f2out  = (const float*)d_in[10];
    const float* b_f2out  = (const float*)d_in[11];
    const float* W_dense  = (const float*)d_in[12];
    const float* b_dense  = (const float*)d_in[13];
    float* out = (float*)d_out;

    // ws: y [8192][128] f32 @0 (4 MB) | prep 240 KB @4 MB.
    // (ws_size >= 8.45 MB established empirically: R1 used that much with
    //  results bit-identical to a 4 MB-only layout.)
    float*    y    = (float*)d_ws;
    unsigned* prep = (unsigned*)((char*)d_ws + (4u << 20));
    const unsigned* W1B     = prep;
    const unsigned* W2B     = prep + 4096;
    const unsigned* in2f_h  = prep + 12288, *in2f_l  = prep + 20480;
    const unsigned* f2out_h = prep + 28672, *f2out_l = prep + 36864;
    const unsigned* dense_h = prep + 45056, *dense_l = prep + 53248;

    const int MG_LDS  = 17920 * 4;   // 71680 B
    const int INT_LDS = 18592 * 4;   // 74368 B
    (void)hipFuncSetAttribute((const void*)mgemm_kernel,
        hipFuncAttributeMaxDynamicSharedMemorySize, MG_LDS);
    (void)hipFuncSetAttribute((const void*)interaction_kernel,
        hipFuncAttributeMaxDynamicSharedMemorySize, INT_LDS);

    // K0: weight prep (bf16 convert/pad/split)
    prep_kernel<<<144, 256, 0, stream>>>(W_f1, W_f2, W_in2f, W_f2out, W_dense, prep);
    // K1: y = x @ W_in2f^T
    mgemm_kernel<<<128, 256, MG_LDS, stream>>>(x, in2f_h, in2f_l, nullptr, 0, y);
    // K2: filter net + cutoff + gather + aggregate -> d_out
    interaction_kernel<<<8192, 256, INT_LDS, stream>>>(
        rij, nbrs, mask, fij, b_f1, b_f2, W1B, W2B, y, out);
    // K3a: t = ssp(ssp(v @ W_f2out^T + b_f2out)), in-place
    mgemm_kernel<<<128, 256, MG_LDS, stream>>>(out, f2out_h, f2out_l, b_f2out, 2, out);
    // K3b: out = t @ W_dense^T + b_dense, in-place
    mgemm_kernel<<<128, 256, MG_LDS, stream>>>(out, dense_h, dense_l, b_dense, 0, out);
}